// Round 7
// baseline (80.353 us; speedup 1.0000x reference)
//
#include <hip/hip_runtime.h>
#include <hip/hip_fp16.h>

// KnnExpansion: out[f, n] = sum_k alpha[i[n,k], f] * exp(-0.5 * d[n,k] / sigma^2)
// N=131072, K=32, M=65536, F=64.
//
// Model (r1-r6): gather is bound by outstanding-capacity/latency on the
// random-row path (schedule-independent 67us at f16). Lever: raise L2 hit
// rate to ~100% by GLOBAL temporal phasing. All 2048 blocks are co-resident;
// each processes its neighbors in 4 phases by index QUARTILE (2 MiB table
// slice -> resident in every XCD's 4 MiB L2).
//  prep:  per query, partition the 32 (idx, w=exp(c*d)) pairs by quartile
//         (ballot-rank in-wave), pack u32 = (idx<<16)|f16(w) -> combo[n][32].
//  main:  8 waves x 8 queries per block; phase p handles sorted positions
//         [8p, 8p+8) (static unroll -> natural MLP); register accumulators;
//         LDS-transposed coalesced [F,N] store.

#define N_Q    131072
#define K_NB   32
#define F_CH   64
#define M_ROWS 65536

// ---- pre-pass 1: alpha f32 -> f16 (streaming, ~3us) ----
__global__ __launch_bounds__(256) void cvt_alpha_f16(
    const float* __restrict__ alpha, __half* __restrict__ a16)
{
    const int t = blockIdx.x * 256 + threadIdx.x;
    const float4 v0 = ((const float4*)alpha)[(size_t)t * 2 + 0];
    const float4 v1 = ((const float4*)alpha)[(size_t)t * 2 + 1];
    union { __half2 h2[4]; uint4 u; } pk;
    pk.h2[0] = __floats2half2_rn(v0.x, v0.y);
    pk.h2[1] = __floats2half2_rn(v0.z, v0.w);
    pk.h2[2] = __floats2half2_rn(v1.x, v1.y);
    pk.h2[3] = __floats2half2_rn(v1.z, v1.w);
    ((uint4*)a16)[t] = pk.u;
}

// ---- pre-pass 2: per-query quartile partition + weight precompute ----
// one wave per query-group; lanes 0..31: d -> w; lanes 32..63: idx.
__global__ __launch_bounds__(512) void prep_combo(
    const float* __restrict__ dmat,   // [N, 32]
    const int*   __restrict__ imat,   // [N, 32]
    const float* __restrict__ sigma,  // [1]
    unsigned*    __restrict__ combo)  // [N, 32] packed (idx<<16 | w_f16)
{
    const int lane = threadIdx.x & 63;
    const int wave = threadIdx.x >> 6;     // 8 waves
    const int n0   = blockIdx.x * 64;

    const float s = sigma[0];
    const float c = -0.5f / (s * s);

    for (int qi = 0; qi < 8; ++qi) {
        const int n = n0 + wave * 8 + qi;

        float wv = 0.0f;
        int   iv = 0;
        if (lane < 32) {
            wv = __expf(c * __builtin_nontemporal_load(
                                &dmat[(size_t)n * K_NB + lane]));
        } else {
            iv = __builtin_nontemporal_load(
                     &imat[(size_t)n * K_NB + (lane - 32)]);
        }

        // f16 bits of w (valid on lanes<32); partner fetch for upper half
        const unsigned hbits = (unsigned)__half_as_ushort(__float2half_rn(wv));
        const unsigned hb = (unsigned)__shfl((int)hbits, lane & 31);

        const int  quart = (iv >> 14) & 3;           // idx / 16384
        const bool hi    = (lane >= 32);

        const unsigned long long m0 = __ballot(hi && quart == 0);
        const unsigned long long m1 = __ballot(hi && quart == 1);
        const unsigned long long m2 = __ballot(hi && quart == 2);
        const unsigned long long m3 = __ballot(hi && quart == 3);
        const int b1 = __popcll(m0);
        const int b2 = b1 + __popcll(m1);
        const int b3 = b2 + __popcll(m2);

        const unsigned long long mq =
            (quart == 0) ? m0 : (quart == 1) ? m1 : (quart == 2) ? m2 : m3;
        const int bq =
            (quart == 0) ? 0 : (quart == 1) ? b1 : (quart == 2) ? b2 : b3;

        const unsigned long long below = (1ull << lane) - 1ull;
        const int pos = bq + __popcll(mq & below);

        if (hi) {
            const unsigned pk = ((unsigned)iv << 16) | (hb & 0xFFFFu);
            combo[(size_t)n * K_NB + pos] = pk;
        }
    }
}

// ---- main: 4-phase L2-resident gather ----
__global__ __launch_bounds__(512) void knn_exp_phased(
    const unsigned* __restrict__ combo,  // [N, 32] sorted by quartile
    const __half*   __restrict__ a16,    // [65536, 64]
    float*          __restrict__ out)    // [64, N]
{
    __shared__ float tile[64][65];       // +1 pad: conflict-free columns

    const int lane = threadIdx.x & 63;
    const int wave = threadIdx.x >> 6;   // 8 waves x 8 queries
    const int n0   = blockIdx.x * 64;
    const unsigned lane2 = (unsigned)lane * 2;

    unsigned pv[8];
    float    acc[8];
    #pragma unroll
    for (int qi = 0; qi < 8; ++qi) {
        const int n = n0 + wave * 8 + qi;
        pv[qi]  = __builtin_nontemporal_load(
                      &combo[(size_t)n * K_NB + (lane & 31)]);
        acc[qi] = 0.0f;
    }

    // phase p: sorted positions [8p, 8p+8) ~= quartile p (2 MiB slice).
    // All blocks run phases in lockstep-ish (all co-resident from t=0),
    // so the chip-wide gather working set is ~2-3 MiB -> L2-resident.
    #pragma unroll
    for (int p = 0; p < 4; ++p) {
        #pragma unroll
        for (int qi = 0; qi < 8; ++qi) {
            #pragma unroll
            for (int j = 0; j < 8; ++j) {
                const unsigned pk = (unsigned)__builtin_amdgcn_readlane(
                    (int)pv[qi], p * 8 + j);              // SGPR
                __half_raw hr; hr.x = (unsigned short)(pk & 0xFFFFu);
                const float w = __half2float(__half(hr)); // scalar->VALU cvt
                const unsigned off = ((pk >> 16) << 7) + lane2;
                const __half av = *(const __half*)((const char*)a16 + off);
                acc[qi] = fmaf(w, __half2float(av), acc[qi]);
            }
        }
    }

    #pragma unroll
    for (int qi = 0; qi < 8; ++qi)
        tile[wave * 8 + qi][lane] = acc[qi];

    __syncthreads();

    // coalesced [F, N] store: each wave writes 8 channel-rows of 64 floats
    #pragma unroll
    for (int fi = 0; fi < 8; ++fi) {
        const int f = wave * 8 + fi;
        __builtin_nontemporal_store(tile[lane][f],
                                    &out[(size_t)f * N_Q + n0 + lane]);
    }
}

// ---- fallback A: round-4 f16 kernel (needs only 8 MiB ws) ----
__global__ __launch_bounds__(256) void knn_exp_f16(
    const float*  __restrict__ dmat,
    const int*    __restrict__ imat,
    const __half* __restrict__ a16,
    const float*  __restrict__ sigma,
    float*        __restrict__ out)
{
    __shared__ float tile[64][65];
    const int lane = threadIdx.x & 63;
    const int wave = threadIdx.x >> 6;
    const int n0   = blockIdx.x * 64;
    const float s = sigma[0];
    const float c = -0.5f / (s * s);

    for (int qi = 0; qi < 16; ++qi) {
        const int q = wave * 16 + qi;
        const int n = n0 + q;
        float wv = 0.0f;
        int   iv = 0;
        if (lane < 32) {
            wv = __expf(c * dmat[(size_t)n * K_NB + lane]);
        } else {
            iv = imat[(size_t)n * K_NB + (lane - 32)];
        }
        float a0 = 0.0f, a1 = 0.0f, a2 = 0.0f, a3 = 0.0f;
        #pragma unroll
        for (int k = 0; k < K_NB; k += 4) {
            const float w0 = __int_as_float(
                __builtin_amdgcn_readlane(__float_as_int(wv), k + 0));
            const int   i0 = __builtin_amdgcn_readlane(iv, 32 + k + 0);
            const float w1 = __int_as_float(
                __builtin_amdgcn_readlane(__float_as_int(wv), k + 1));
            const int   i1 = __builtin_amdgcn_readlane(iv, 32 + k + 1);
            const float w2 = __int_as_float(
                __builtin_amdgcn_readlane(__float_as_int(wv), k + 2));
            const int   i2 = __builtin_amdgcn_readlane(iv, 32 + k + 2);
            const float w3 = __int_as_float(
                __builtin_amdgcn_readlane(__float_as_int(wv), k + 3));
            const int   i3 = __builtin_amdgcn_readlane(iv, 32 + k + 3);
            a0 = fmaf(w0, __half2float(a16[(size_t)i0 * F_CH + lane]), a0);
            a1 = fmaf(w1, __half2float(a16[(size_t)i1 * F_CH + lane]), a1);
            a2 = fmaf(w2, __half2float(a16[(size_t)i2 * F_CH + lane]), a2);
            a3 = fmaf(w3, __half2float(a16[(size_t)i3 * F_CH + lane]), a3);
        }
        tile[q][lane] = (a0 + a1) + (a2 + a3);
    }
    __syncthreads();
    #pragma unroll
    for (int fi = 0; fi < 16; ++fi) {
        const int f = wave * 16 + fi;
        out[(size_t)f * N_Q + n0 + lane] = tile[lane][f];
    }
}

// ---- fallback B: pure fp32 (no workspace) ----
__global__ __launch_bounds__(256) void knn_exp_f32(
    const float* __restrict__ dmat,
    const int*   __restrict__ imat,
    const float* __restrict__ alpha,
    const float* __restrict__ sigma,
    float*       __restrict__ out)
{
    __shared__ float tile[64][65];
    const int lane = threadIdx.x & 63;
    const int wave = threadIdx.x >> 6;
    const int n0   = blockIdx.x * 64;
    const float s = sigma[0];
    const float c = -0.5f / (s * s);

    for (int qi = 0; qi < 16; ++qi) {
        const int q = wave * 16 + qi;
        const int n = n0 + q;
        float wv = 0.0f;
        int   iv = 0;
        if (lane < 32) {
            wv = __expf(c * dmat[(size_t)n * K_NB + lane]);
        } else {
            iv = imat[(size_t)n * K_NB + (lane - 32)];
        }
        float acc = 0.0f;
        #pragma unroll
        for (int k = 0; k < K_NB; ++k) {
            const float wk = __int_as_float(
                __builtin_amdgcn_readlane(__float_as_int(wv), k));
            const int   ik = __builtin_amdgcn_readlane(iv, 32 + k);
            acc = fmaf(wk, alpha[(size_t)ik * F_CH + lane], acc);
        }
        tile[q][lane] = acc;
    }
    __syncthreads();
    #pragma unroll
    for (int fi = 0; fi < 16; ++fi) {
        const int f = wave * 16 + fi;
        out[(size_t)f * N_Q + n0 + lane] = tile[lane][f];
    }
}

extern "C" void kernel_launch(void* const* d_in, const int* in_sizes, int n_in,
                              void* d_out, int out_size, void* d_ws, size_t ws_size,
                              hipStream_t stream) {
    const float* dmat  = (const float*)d_in[0];
    const int*   imat  = (const int*)d_in[1];
    const float* alpha = (const float*)d_in[2];
    const float* sigma = (const float*)d_in[3];
    float* out = (float*)d_out;

    const size_t bytes_a16   = (size_t)M_ROWS * F_CH * sizeof(__half);   // 8 MiB
    const size_t bytes_combo = (size_t)N_Q * K_NB * sizeof(unsigned);    // 16 MiB

    if (ws_size >= bytes_a16 + bytes_combo) {
        __half*   a16   = (__half*)d_ws;
        unsigned* combo = (unsigned*)((char*)d_ws + bytes_a16);
        hipLaunchKernelGGL(cvt_alpha_f16, dim3(M_ROWS * F_CH / 8 / 256),
                           dim3(256), 0, stream, alpha, a16);
        hipLaunchKernelGGL(prep_combo, dim3(N_Q / 64), dim3(512), 0, stream,
                           dmat, imat, sigma, combo);
        hipLaunchKernelGGL(knn_exp_phased, dim3(N_Q / 64), dim3(512), 0,
                           stream, combo, a16, out);
    } else if (ws_size >= bytes_a16) {
        __half* a16 = (__half*)d_ws;
        hipLaunchKernelGGL(cvt_alpha_f16, dim3(M_ROWS * F_CH / 8 / 256),
                           dim3(256), 0, stream, alpha, a16);
        hipLaunchKernelGGL(knn_exp_f16, dim3(N_Q / 64), dim3(256), 0,
                           stream, dmat, imat, a16, sigma, out);
    } else {
        hipLaunchKernelGGL(knn_exp_f32, dim3(N_Q / 64), dim3(256), 0, stream,
                           dmat, imat, alpha, sigma, out);
    }
}

// Round 8
// 70.764 us; speedup vs baseline: 1.1355x; 1.1355x over previous
//
#include <hip/hip_runtime.h>
#include <hip/hip_fp16.h>

// KnnExpansion: out[f, n] = sum_k alpha[i[n,k], f] * exp(-0.5 * d[n,k] / sigma^2)
// N=131072, K=32, M=65536, F=64.
//
// Model (r1-r7): gather bound by outstanding-capacity/latency; 4-phase
// quartile partitioning makes the gather ~L2-resident (main 67->47us,
// proven r7), but a separate prep pass cost +30us. This round FUSES the
// partition into the main kernel: in-register quartile rank (ballot+popc),
// bounce through wave-local LDS scratch (no barrier needed), then the
// identical r7 phased consume loop. Eliminates 32 MiB combo traffic and
// the whole prep dispatch.

#define N_Q    131072
#define K_NB   32
#define F_CH   64
#define M_ROWS 65536

// ---- pre-pass: alpha f32 -> f16 (streaming, ~3us) ----
__global__ __launch_bounds__(256) void cvt_alpha_f16(
    const float* __restrict__ alpha, __half* __restrict__ a16)
{
    const int t = blockIdx.x * 256 + threadIdx.x;
    const float4 v0 = ((const float4*)alpha)[(size_t)t * 2 + 0];
    const float4 v1 = ((const float4*)alpha)[(size_t)t * 2 + 1];
    union { __half2 h2[4]; uint4 u; } pk;
    pk.h2[0] = __floats2half2_rn(v0.x, v0.y);
    pk.h2[1] = __floats2half2_rn(v0.z, v0.w);
    pk.h2[2] = __floats2half2_rn(v1.x, v1.y);
    pk.h2[3] = __floats2half2_rn(v1.z, v1.w);
    ((uint4*)a16)[t] = pk.u;
}

// ---- fused main: in-register quartile sort + 4-phase L2-resident gather ----
__global__ __launch_bounds__(512) void knn_exp_fused(
    const float*  __restrict__ dmat,   // [N, 32]
    const int*    __restrict__ imat,   // [N, 32]
    const __half* __restrict__ a16,    // [65536, 64]
    const float*  __restrict__ sigma,  // [1]
    float*        __restrict__ out)    // [64, N]
{
    __shared__ float    tile[64][65];        // +1 pad: conflict-free columns
    __shared__ unsigned sortbuf[8][8][32];   // wave-local sort scratch (8 KiB)

    const int lane = threadIdx.x & 63;
    const int wave = threadIdx.x >> 6;       // 8 waves x 8 queries
    const int n0   = blockIdx.x * 64;
    const unsigned lane2 = (unsigned)lane * 2;
    const bool hi  = (lane >= 32);

    const float s = sigma[0];
    const float c = -0.5f / (s * s);

    // ---- inline prep: per query, pack (idx<<16 | f16(w)) sorted by quartile
    #pragma unroll
    for (int qi = 0; qi < 8; ++qi) {
        const int n = n0 + wave * 8 + qi;

        float wv = 0.0f;
        int   iv = 0;
        if (!hi) {
            wv = __expf(c * __builtin_nontemporal_load(
                                &dmat[(size_t)n * K_NB + lane]));
        } else {
            iv = __builtin_nontemporal_load(
                     &imat[(size_t)n * K_NB + (lane - 32)]);
        }

        // f16 bits of w live on lanes<32; hi lanes pull their partner's
        const unsigned hbits = (unsigned)__half_as_ushort(__float2half_rn(wv));
        const unsigned hb    = (unsigned)__shfl((int)hbits, lane & 31);

        // quartile rank among the 32 hi lanes (stable partition)
        const int quart = (iv >> 14) & 3;
        const unsigned long long m0 = __ballot(hi && quart == 0);
        const unsigned long long m1 = __ballot(hi && quart == 1);
        const unsigned long long m2 = __ballot(hi && quart == 2);
        const unsigned long long m3 = __ballot(hi && quart == 3);
        const int b1 = __popcll(m0);
        const int b2 = b1 + __popcll(m1);
        const int b3 = b2 + __popcll(m2);
        const unsigned long long mq =
            (quart == 0) ? m0 : (quart == 1) ? m1 : (quart == 2) ? m2 : m3;
        const int bq =
            (quart == 0) ? 0 : (quart == 1) ? b1 : (quart == 2) ? b2 : b3;
        const unsigned long long below = (1ull << lane) - 1ull;
        const int pos = bq + __popcll(mq & below);

        if (hi)
            sortbuf[wave][qi][pos] = ((unsigned)iv << 16) | (hb & 0xFFFFu);
    }

    // wave-local RAW through LDS: compiler inserts lgkmcnt, no barrier needed
    unsigned pv[8];
    float    acc[8];
    #pragma unroll
    for (int qi = 0; qi < 8; ++qi) {
        pv[qi]  = sortbuf[wave][qi][lane & 31];
        acc[qi] = 0.0f;
    }

    // ---- proven r7 consume: phase p ~= quartile p (2 MiB L2-resident slice)
    #pragma unroll
    for (int p = 0; p < 4; ++p) {
        #pragma unroll
        for (int qi = 0; qi < 8; ++qi) {
            #pragma unroll
            for (int j = 0; j < 8; ++j) {
                const unsigned pk = (unsigned)__builtin_amdgcn_readlane(
                    (int)pv[qi], p * 8 + j);              // SGPR
                __half_raw hr; hr.x = (unsigned short)(pk & 0xFFFFu);
                const float w = __half2float(__half(hr));
                const unsigned off = ((pk >> 16) << 7) + lane2;
                const __half av = *(const __half*)((const char*)a16 + off);
                acc[qi] = fmaf(w, __half2float(av), acc[qi]);
            }
        }
    }

    #pragma unroll
    for (int qi = 0; qi < 8; ++qi)
        tile[wave * 8 + qi][lane] = acc[qi];

    __syncthreads();

    // coalesced [F, N] store: each wave writes 8 channel-rows of 64 floats
    #pragma unroll
    for (int fi = 0; fi < 8; ++fi) {
        const int f = wave * 8 + fi;
        __builtin_nontemporal_store(tile[lane][f],
                                    &out[(size_t)f * N_Q + n0 + lane]);
    }
}

// ---- fallback A: round-4 f16 kernel (needs only 8 MiB ws) ----
__global__ __launch_bounds__(256) void knn_exp_f16(
    const float*  __restrict__ dmat,
    const int*    __restrict__ imat,
    const __half* __restrict__ a16,
    const float*  __restrict__ sigma,
    float*        __restrict__ out)
{
    __shared__ float tile[64][65];
    const int lane = threadIdx.x & 63;
    const int wave = threadIdx.x >> 6;
    const int n0   = blockIdx.x * 64;
    const float s = sigma[0];
    const float c = -0.5f / (s * s);

    for (int qi = 0; qi < 16; ++qi) {
        const int q = wave * 16 + qi;
        const int n = n0 + q;
        float wv = 0.0f;
        int   iv = 0;
        if (lane < 32) {
            wv = __expf(c * dmat[(size_t)n * K_NB + lane]);
        } else {
            iv = imat[(size_t)n * K_NB + (lane - 32)];
        }
        float a0 = 0.0f, a1 = 0.0f, a2 = 0.0f, a3 = 0.0f;
        #pragma unroll
        for (int k = 0; k < K_NB; k += 4) {
            const float w0 = __int_as_float(
                __builtin_amdgcn_readlane(__float_as_int(wv), k + 0));
            const int   i0 = __builtin_amdgcn_readlane(iv, 32 + k + 0);
            const float w1 = __int_as_float(
                __builtin_amdgcn_readlane(__float_as_int(wv), k + 1));
            const int   i1 = __builtin_amdgcn_readlane(iv, 32 + k + 1);
            const float w2 = __int_as_float(
                __builtin_amdgcn_readlane(__float_as_int(wv), k + 2));
            const int   i2 = __builtin_amdgcn_readlane(iv, 32 + k + 2);
            const float w3 = __int_as_float(
                __builtin_amdgcn_readlane(__float_as_int(wv), k + 3));
            const int   i3 = __builtin_amdgcn_readlane(iv, 32 + k + 3);
            a0 = fmaf(w0, __half2float(a16[(size_t)i0 * F_CH + lane]), a0);
            a1 = fmaf(w1, __half2float(a16[(size_t)i1 * F_CH + lane]), a1);
            a2 = fmaf(w2, __half2float(a16[(size_t)i2 * F_CH + lane]), a2);
            a3 = fmaf(w3, __half2float(a16[(size_t)i3 * F_CH + lane]), a3);
        }
        tile[q][lane] = (a0 + a1) + (a2 + a3);
    }
    __syncthreads();
    #pragma unroll
    for (int fi = 0; fi < 16; ++fi) {
        const int f = wave * 16 + fi;
        out[(size_t)f * N_Q + n0 + lane] = tile[lane][f];
    }
}

// ---- fallback B: pure fp32 (no workspace) ----
__global__ __launch_bounds__(256) void knn_exp_f32(
    const float* __restrict__ dmat,
    const int*   __restrict__ imat,
    const float* __restrict__ alpha,
    const float* __restrict__ sigma,
    float*       __restrict__ out)
{
    __shared__ float tile[64][65];
    const int lane = threadIdx.x & 63;
    const int wave = threadIdx.x >> 6;
    const int n0   = blockIdx.x * 64;
    const float s = sigma[0];
    const float c = -0.5f / (s * s);

    for (int qi = 0; qi < 16; ++qi) {
        const int q = wave * 16 + qi;
        const int n = n0 + q;
        float wv = 0.0f;
        int   iv = 0;
        if (lane < 32) {
            wv = __expf(c * dmat[(size_t)n * K_NB + lane]);
        } else {
            iv = imat[(size_t)n * K_NB + (lane - 32)];
        }
        float acc = 0.0f;
        #pragma unroll
        for (int k = 0; k < K_NB; ++k) {
            const float wk = __int_as_float(
                __builtin_amdgcn_readlane(__float_as_int(wv), k));
            const int   ik = __builtin_amdgcn_readlane(iv, 32 + k);
            acc = fmaf(wk, alpha[(size_t)ik * F_CH + lane], acc);
        }
        tile[q][lane] = acc;
    }
    __syncthreads();
    #pragma unroll
    for (int fi = 0; fi < 16; ++fi) {
        const int f = wave * 16 + fi;
        out[(size_t)f * N_Q + n0 + lane] = tile[lane][f];
    }
}

extern "C" void kernel_launch(void* const* d_in, const int* in_sizes, int n_in,
                              void* d_out, int out_size, void* d_ws, size_t ws_size,
                              hipStream_t stream) {
    const float* dmat  = (const float*)d_in[0];
    const int*   imat  = (const int*)d_in[1];
    const float* alpha = (const float*)d_in[2];
    const float* sigma = (const float*)d_in[3];
    float* out = (float*)d_out;

    const size_t bytes_a16 = (size_t)M_ROWS * F_CH * sizeof(__half);  // 8 MiB

    if (ws_size >= bytes_a16) {
        __half* a16 = (__half*)d_ws;
        hipLaunchKernelGGL(cvt_alpha_f16, dim3(M_ROWS * F_CH / 8 / 256),
                           dim3(256), 0, stream, alpha, a16);
        hipLaunchKernelGGL(knn_exp_fused, dim3(N_Q / 64), dim3(512), 0,
                           stream, dmat, imat, a16, sigma, out);
    } else {
        hipLaunchKernelGGL(knn_exp_f32, dim3(N_Q / 64), dim3(256), 0, stream,
                           dmat, imat, alpha, sigma, out);
    }
}